// Round 1
// baseline (600.353 us; speedup 1.0000x reference)
//
#include <hip/hip_runtime.h>
#include <math.h>

#define Bsz 32
#define Nn 207
#define Tt 12
#define Cc 2
#define HORr 12
#define DIDd 64
#define Hh 128
#define NBb 3
#define CONCATk 2560
#define BN (Bsz*Nn)           // 6624
#define ROWS (BN*Cc)          // 13248 = 828*16
#define XSTRIDE (CONCATk*Cc)  // 5120

typedef unsigned short u16;
typedef __attribute__((ext_vector_type(8))) short bf16x8;
typedef __attribute__((ext_vector_type(4))) float f32x4;

__device__ inline u16 f2b(float f) {
  unsigned u = __builtin_bit_cast(unsigned, f);
  u += 0x7fffu + ((u >> 16) & 1u);          // RNE
  return (u16)(u >> 16);
}
__device__ inline float b2f(u16 b) {
  unsigned u = ((unsigned)b) << 16;
  return __builtin_bit_cast(float, u);
}
__device__ inline void gld16(const void* g, void* l) {
  __builtin_amdgcn_global_load_lds((const __attribute__((address_space(1))) void*)g,
                                   (__attribute__((address_space(3))) void*)l, 16, 0, 0);
}

// ---------------- K1: time gates + h_in + level + zero f_acc ----------------
__global__ __launch_bounds__(128) void k_timegate(
    const float* __restrict__ hist, const float* __restrict__ tod,
    const float* __restrict__ emb,
    const float* __restrict__ w1, const float* __restrict__ b1,
    const float* __restrict__ w2, const float* __restrict__ b2,
    const float* __restrict__ w3, const float* __restrict__ b3,
    float* __restrict__ h_in, float* __restrict__ level,
    float* __restrict__ tgf, float* __restrict__ f_acc)
{
  int bn = blockIdx.x;
  int n = bn % Nn;
  __shared__ float s_in[76];
  __shared__ float s_tg[128];
  __shared__ float s_tgb[12];
  __shared__ float s_h[24];
  int tid = threadIdx.x;
  if (tid < 64) s_in[tid] = emb[n*64 + tid];
  else if (tid < 76) s_in[tid] = tod[bn*12 + (tid - 64)];
  __syncthreads();
  float acc = b1[tid];
#pragma unroll 4
  for (int k = 0; k < 76; ++k) acc = fmaf(s_in[k], w1[k*128 + tid], acc);
  s_tg[tid] = fmaxf(acc, 0.f);
  __syncthreads();
  if (tid < 24) {
    int j = tid % 12;
    const float* w = (tid < 12) ? w2 : w3;
    float a = (tid < 12) ? b2[j] : b3[j];
    for (int k = 0; k < 128; ++k) a = fmaf(s_tg[k], w[k*12 + j], a);
    if (tid < 12) tgf[bn*12 + j] = a;
    else s_tgb[j] = a;
  }
  __syncthreads();
  if (tid < 24) {
    int t = tid >> 1;
    float v = hist[bn*24 + tid] / (1.f + s_tgb[t]);
    h_in[bn*24 + tid] = v;
    s_h[tid] = v;
    f_acc[bn*24 + tid] = 0.f;
  }
  __syncthreads();
  if (tid < 2) {
    float m = s_h[tid];
    for (int t = 1; t < 12; ++t) m = fmaxf(m, s_h[t*2 + tid]);
    level[bn*2 + tid] = m;
  }
}

// ---------------- K2: dp[n,m] = exp(10 * <emb_n, emb_m>) ----------------
__global__ __launch_bounds__(256) void k_dp(const float* __restrict__ emb,
                                            float* __restrict__ dp)
{
  int n = blockIdx.x;
  __shared__ float e[64];
  int tid = threadIdx.x;
  if (tid < 64) e[tid] = emb[n*64 + tid];
  __syncthreads();
  if (tid < Nn) {
    float a = 0.f;
#pragma unroll 8
    for (int k = 0; k < 64; ++k) a = fmaf(e[k], emb[tid*64 + k], a);
    dp[n*Nn + tid] = expf(10.f * a);
  }
}

// ---------------- weight transpose+convert: fp32 [K][N] -> bf16 [N][K] -------
__global__ __launch_bounds__(256) void k_transp(
    const float* __restrict__ src, u16* __restrict__ dst, int K, int N)
{
  int k0 = blockIdx.x*64, n0 = blockIdx.y*64;
  size_t mo = (size_t)blockIdx.z * K * N;
  src += mo; dst += mo;
  __shared__ u16 Ts[64][72];
  int tid = threadIdx.x;
#pragma unroll
  for (int it = 0; it < 4; ++it) {
    int idx = it*256 + tid;
    int r = idx >> 4, q = idx & 15;
    float4 v = *(const float4*)(src + (size_t)(k0 + r)*N + n0 + q*4);
    Ts[r][q*4+0] = f2b(v.x);
    Ts[r][q*4+1] = f2b(v.y);
    Ts[r][q*4+2] = f2b(v.z);
    Ts[r][q*4+3] = f2b(v.w);
  }
  __syncthreads();
#pragma unroll
  for (int it = 0; it < 2; ++it) {
    int idx = it*256 + tid;
    int nl = idx >> 3, kq = idx & 7;
    u16 o[8];
#pragma unroll
    for (int j = 0; j < 8; ++j) o[j] = Ts[kq*8 + j][nl];
    *(bf16x8*)(dst + (size_t)(n0 + nl)*K + k0 + kq*8) = *(bf16x8*)o;
  }
}

// ---------------- build xb bf16, row-major [r=bn*2+c][k] ---------------------
__global__ __launch_bounds__(256) void k_build_b(
    const float* __restrict__ h_in, const float* __restrict__ level,
    const float* __restrict__ dp, const float* __restrict__ emb,
    u16* __restrict__ xb)
{
  int bn = blockIdx.x;
  int b = bn / Nn, n = bn - b*Nn;
  __shared__ float s_dp[Nn];
  int tid = threadIdx.x;
  for (int m = tid; m < Nn; m += 256) s_dp[m] = dp[n*Nn + m];
  __syncthreads();
  float lev[2] = {level[bn*2], level[bn*2+1]};
  float inv[2] = {1.f/(lev[0]+1e-8f), 1.f/(lev[1]+1e-8f)};
  const float* hb = h_in + (size_t)b*Nn*24;
  for (int s = tid; s < 640; s += 256) {
    int c = s / 320, ks = s - c*320;
    u16 o[8];
#pragma unroll
    for (int j = 0; j < 8; ++j) {
      int k = ks*8 + j;
      float v;
      if (k < 12) v = h_in[bn*24 + k*2 + c] * inv[c];
      else if (k < 2496) {
        int q = k - 12; int m = q / 12, t = q - m*12;
        v = fmaxf((hb[m*24 + t*2 + c]*s_dp[m] - lev[c]) * inv[c], 0.f);
      } else v = emb[n*64 + (k - 2496)];
      o[j] = f2b(v);
    }
    *(bf16x8*)(xb + (size_t)(bn*2 + c)*2560 + ks*8) = *(bf16x8*)o;
  }
}

// ---------------- fused N-BEATS block: fc0->h1->h2->h3 + fore + back ---------
// Round-1 restructure for occupancy (was: 32-row tiles, 65 KB LDS, 2 blk/CU,
// single-buffered back staging -> 18% occupancy, all pipes <13% busy).
// Now: 16-row tiles (grid 828), ~39 KB LDS -> 4 blk/CU capacity, back phase
// double-buffered at 64-col granularity with 1 barrier/tile and register
// prefetch of x-old/bias. Epilogues write directly from MFMA fragments.
// FINAL=0: RMW xb (bf16). FINAL=1: fully-coalesced float2 stores to d_out.
template<int FINAL>
__global__ __launch_bounds__(256, 4) void k_mega(
    u16* __restrict__ xb,
    const u16* __restrict__ W0t, const float* __restrict__ b0,
    const u16* __restrict__ W1t, const float* __restrict__ b1,
    const u16* __restrict__ W2t, const float* __restrict__ b2,
    const float* __restrict__ FW, const float* __restrict__ fb,
    const u16* __restrict__ BWt, const float* __restrict__ bbias,
    float* __restrict__ f_acc, float* __restrict__ xf)
{
  __shared__ __attribute__((aligned(16))) u16 As[2048];    // 4 KB: fc0 A dbuf / h storage
  __shared__ __attribute__((aligned(16))) u16 Bs[16384];   // 32 KB: fc0 B dbuf / W1/W2 / BW dbuf
  __shared__ __attribute__((aligned(16))) u16 sFwB[1536];  // 3 KB: FW as bf16
  __shared__ float sFb[12];
  const int tid = threadIdx.x, wv = tid >> 6, lane = tid & 63;
  const int m16 = lane & 15, quad = lane >> 4;
  const int wc = wv * 32;                 // per-wave col base (fc0/h phases)
  const int r0 = blockIdx.x * 16;

  // ---- phase 1: fc0, K=2560, BK=64, double-buffered ----
  const u16* a_src = nullptr; u16* a_dst = nullptr;
  if (tid < 128) {                        // waves 0,1 stage A (wave-uniform branch)
    int a_row = tid >> 3, a_c = tid & 7, a_g = a_c ^ (a_row & 7);
    a_src = xb + (size_t)(r0 + a_row)*2560 + a_g*8;
    a_dst = &As[wv*512];
  }
  const u16* b_src[4]; u16* b_dst[4];
#pragma unroll
  for (int it = 0; it < 4; ++it) {
    int slot = it*256 + tid;
    int nl = slot >> 3, c = slot & 7, g = c ^ (nl & 7);
    b_src[it] = W0t + (size_t)nl*2560 + g*8;
    b_dst[it] = &Bs[(it*256 + wv*64)*8];
  }
  if (tid < 128) gld16(a_src, a_dst);
#pragma unroll
  for (int it = 0; it < 4; ++it) gld16(b_src[it], b_dst[it]);

  f32x4 acc[2] = {};
  for (int i = 0; i < 40; ++i) {
    const int buf = i & 1;
    __syncthreads();
    if (i < 39) {
      const int nb = buf ^ 1;
      if (tid < 128) gld16(a_src + (i+1)*64, a_dst + nb*1024);
#pragma unroll
      for (int it = 0; it < 4; ++it)
        gld16(b_src[it] + (i+1)*64, b_dst[it] + nb*8192);
    }
    const u16* Ab = &As[buf*1024];
    const u16* Bb = &Bs[buf*8192];
#pragma unroll
    for (int ks = 0; ks < 2; ++ks) {
      int cb = ks*4 + quad;
      bf16x8 a = *(const bf16x8*)&Ab[(m16*8 + (cb ^ (m16 & 7)))*8];
#pragma unroll
      for (int j = 0; j < 2; ++j) {
        int nl = wc + j*16 + m16;
        bf16x8 b = *(const bf16x8*)&Bb[(nl*8 + (cb ^ (nl & 7)))*8];
        acc[j] = __builtin_amdgcn_mfma_f32_16x16x32_bf16(a, b, acc[j], 0, 0, 0);
      }
    }
  }

  // helpers for H x H phases (K=128, 16 chunks, XOR-16 swizzle)
  auto stageW = [&](const u16* W) {
#pragma unroll
    for (int it = 0; it < 8; ++it) {
      int slot = it*256 + tid;
      int nl = slot >> 4, c = slot & 15, g = c ^ (nl & 15);
      gld16(W + (size_t)nl*128 + g*8, &Bs[(it*256 + wv*64)*8]);
    }
  };
  auto writeH = [&](const f32x4* ac, const float* bias) {
#pragma unroll
    for (int j = 0; j < 2; ++j) {
      int col = wc + j*16 + m16;
      float bv = bias[col];
#pragma unroll
      for (int reg = 0; reg < 4; ++reg) {
        int row = quad*4 + reg;
        int chunk = col >> 3;
        As[(row*16 + (chunk ^ row))*8 + (col & 7)] =
            f2b(fmaxf(ac[j][reg] + bv, 0.f));
      }
    }
  };
  auto mm128 = [&](f32x4* ac) {
#pragma unroll
    for (int ks = 0; ks < 4; ++ks) {
      int cb = ks*4 + quad;
      bf16x8 a = *(const bf16x8*)&As[(m16*16 + (cb ^ m16))*8];
#pragma unroll
      for (int j = 0; j < 2; ++j) {
        int nl = wc + j*16 + m16;
        bf16x8 b = *(const bf16x8*)&Bs[(nl*16 + (cb ^ (nl & 15)))*8];
        ac[j] = __builtin_amdgcn_mfma_f32_16x16x32_bf16(a, b, ac[j], 0, 0, 0);
      }
    }
  };

  __syncthreads();                 // fc0 LDS reads done
  stageW(W1t);
  for (int s = tid; s < 1536; s += 256) sFwB[s] = f2b(FW[s]);
  if (tid < 12) sFb[tid] = fb[tid];
  writeH(acc, b0);                 // h1 -> As
  __syncthreads();

  f32x4 acc2[2] = {};
  mm128(acc2);
  __syncthreads();
  stageW(W2t);
  writeH(acc2, b1);                // h2 -> As
  __syncthreads();

  f32x4 acc3[2] = {};
  mm128(acc3);
  __syncthreads();
  writeH(acc3, b2);                // h3 -> As (stays for back phase)
  __syncthreads();                 // h3 visible to all waves

  // ---- back phase prologue: stage tile 0 + prefetch, overlapped with fore ----
  auto stageBW = [&](int nt, int buf) {
    const int n0 = nt*64;
#pragma unroll
    for (int it = 0; it < 4; ++it) {
      int slot = it*256 + tid;
      int nl = slot >> 4, c = slot & 15, g = c ^ (nl & 15);
      gld16(BWt + (size_t)(n0 + nl)*128 + g*8,
            &Bs[buf*8192 + (it*256 + wv*64)*8]);
    }
  };
  const int colL = wv*16 + m16;    // 0..63 within a 64-col tile
  float bb_cur, bb_nxt;
  u16 xo_cur[4], xo_nxt[4];
  stageBW(0, 0);
  bb_cur = bbias[colL];
#pragma unroll
  for (int reg = 0; reg < 4; ++reg)
    xo_cur[reg] = xb[(size_t)(r0 + quad*4 + reg)*2560 + colL];

  // forecast accumulation from As(h3) — overlaps tile-0 staging latency
  for (int o = tid; o < 192; o += 256) {
    int row = o / 12, t = o - (o/12)*12;
    float a = sFb[t];
#pragma unroll
    for (int chunk = 0; chunk < 16; ++chunk) {
      const u16* hp = &As[(row*16 + (chunk ^ row))*8];
#pragma unroll
      for (int j = 0; j < 8; ++j)
        a = fmaf(b2f(hp[j]), b2f(sFwB[(chunk*8 + j)*12 + t]), a);
    }
    f_acc[(size_t)(r0 + row)*12 + t] += a;
  }

  // ---- phase 5: back GEMM over 40 column tiles of 64, double-buffered ----
  for (int nt = 0; nt < 40; ++nt) {
    const int buf = nt & 1;
    __syncthreads();               // stage(nt) complete; Bs[buf^1] reads done
    if (nt < 39) {
      stageBW(nt+1, buf ^ 1);
      int gc = (nt+1)*64 + colL;
      bb_nxt = bbias[gc];
#pragma unroll
      for (int reg = 0; reg < 4; ++reg)
        xo_nxt[reg] = xb[(size_t)(r0 + quad*4 + reg)*2560 + gc];
    }
    f32x4 bacc = {};
#pragma unroll
    for (int ks = 0; ks < 4; ++ks) {
      int cb = ks*4 + quad;
      bf16x8 a = *(const bf16x8*)&As[(m16*16 + (cb ^ m16))*8];
      bf16x8 b = *(const bf16x8*)&Bs[buf*8192 + (colL*16 + (cb ^ m16))*8];
      bacc = __builtin_amdgcn_mfma_f32_16x16x32_bf16(a, b, bacc, 0, 0, 0);
    }
    const int gcol = nt*64 + colL;
    if constexpr (!FINAL) {
#pragma unroll
      for (int reg = 0; reg < 4; ++reg) {
        float v = fmaxf(b2f(xo_cur[reg]) - (bacc[reg] + bb_cur), 0.f);
        xb[(size_t)(r0 + quad*4 + reg)*2560 + gcol] = f2b(v);
      }
    } else {
#pragma unroll
      for (int pr = 0; pr < 2; ++pr) {
        int R0 = quad*4 + pr*2;    // even row; rows (R0,R0+1) share bn, c=0/1
        float2 o;
        o.x = fmaxf(b2f(xo_cur[pr*2+0]) - (bacc[pr*2+0] + bb_cur), 0.f);
        o.y = fmaxf(b2f(xo_cur[pr*2+1]) - (bacc[pr*2+1] + bb_cur), 0.f);
        int bn = (r0 + R0) >> 1;
        *(float2*)(xf + (size_t)bn*XSTRIDE + (size_t)gcol*2) = o;
      }
    }
#pragma unroll
    for (int reg = 0; reg < 4; ++reg) xo_cur[reg] = xo_nxt[reg];
    bb_cur = bb_nxt;
  }
}

// ---------------- finalize forecast ----------------
__global__ __launch_bounds__(256) void k_forecast(
    const float* __restrict__ f_acc, const float* __restrict__ level,
    const float* __restrict__ tgf, float* __restrict__ outf)
{
  int idx = blockIdx.x*256 + threadIdx.x;
  if (idx >= BN*24) return;
  int bn = idx / 24;
  int rem = idx - bn*24;
  int t = rem >> 1, c = rem & 1;
  float v = f_acc[bn*24 + c*12 + t];
  outf[idx] = v * level[bn*2 + c] * (1.f + tgf[bn*12 + t]);
}

extern "C" void kernel_launch(void* const* d_in, const int* in_sizes, int n_in,
                              void* d_out, int out_size, void* d_ws, size_t ws_size,
                              hipStream_t stream)
{
  const float* hist = (const float*)d_in[0];
  const float* tod  = (const float*)d_in[1];
  const float* emb  = (const float*)d_in[2];
  const float* tg1w = (const float*)d_in[3];
  const float* tg1b = (const float*)d_in[4];
  const float* tg2w = (const float*)d_in[5];
  const float* tg2b = (const float*)d_in[6];
  const float* tg3w = (const float*)d_in[7];
  const float* tg3b = (const float*)d_in[8];
  const float* fc0w = (const float*)d_in[9];
  const float* fc0b = (const float*)d_in[10];
  const float* fcw  = (const float*)d_in[11];
  const float* fcb  = (const float*)d_in[12];
  const float* forew= (const float*)d_in[13];
  const float* foreb= (const float*)d_in[14];
  const float* backw= (const float*)d_in[15];
  const float* backb= (const float*)d_in[16];

  char* w = (char*)d_ws;
  float* h_in  = (float*)w; w += 635904;     // 158976 f32
  float* level = (float*)w; w += 52992;      // 13248 f32
  float* tgf   = (float*)w; w += 317952;     // 79488 f32
  float* dp    = (float*)w; w += 171408;     // 42852 f32
  float* f_acc = (float*)w; w += 635904;     // 158976 f32
  u16* fc0wt   = (u16*)w;   w += 1966080;    // 3 x [128][2560]
  u16* fcwt    = (u16*)w;   w += 196608;     // 6 x [128][128]
  u16* backwt  = (u16*)w;   w += 1966080;    // 3 x [2560][128]
  u16* xb      = (u16*)w;   w += 67829760;   // 13248*2560 bf16

  float* x    = (float*)d_out;                               // [bn][k][c] fp32
  float* outf = (float*)d_out + (size_t)BN*CONCATk*Cc;

  k_transp<<<dim3(40, 2, 3), 256, 0, stream>>>(fc0w, fc0wt, 2560, 128);
  k_transp<<<dim3(2, 2, 6), 256, 0, stream>>>(fcw, fcwt, 128, 128);
  k_transp<<<dim3(2, 40, 3), 256, 0, stream>>>(backw, backwt, 128, 2560);
  k_timegate<<<BN, 128, 0, stream>>>(hist, tod, emb, tg1w, tg1b, tg2w, tg2b,
                                     tg3w, tg3b, h_in, level, tgf, f_acc);
  k_dp<<<Nn, 256, 0, stream>>>(emb, dp);
  k_build_b<<<BN, 256, 0, stream>>>(h_in, level, dp, emb, xb);

  for (int i = 0; i < NBb; ++i) {
    const u16* W0t = fc0wt + (size_t)i*327680;
    const u16* W1t = fcwt + (size_t)(i*2+0)*16384;
    const u16* W2t = fcwt + (size_t)(i*2+1)*16384;
    const u16* BWt = backwt + (size_t)i*327680;
    if (i < NBb-1)
      k_mega<0><<<828, 256, 0, stream>>>(
          xb, W0t, fc0b + i*128, W1t, fcb + (i*2+0)*128, W2t, fcb + (i*2+1)*128,
          forew + (size_t)i*1536, foreb + i*12, BWt, backb + (size_t)i*2560,
          f_acc, nullptr);
    else
      k_mega<1><<<828, 256, 0, stream>>>(
          xb, W0t, fc0b + i*128, W1t, fcb + (i*2+0)*128, W2t, fcb + (i*2+1)*128,
          forew + (size_t)i*1536, foreb + i*12, BWt, backb + (size_t)i*2560,
          f_acc, x);
  }
  k_forecast<<<(BN*24 + 255)/256, 256, 0, stream>>>(f_acc, level, tgf, outf);
}

// Round 2
// 555.256 us; speedup vs baseline: 1.0812x; 1.0812x over previous
//
#include <hip/hip_runtime.h>
#include <math.h>

#define Bsz 32
#define Nn 207
#define Tt 12
#define Cc 2
#define HORr 12
#define DIDd 64
#define Hh 128
#define NBb 3
#define CONCATk 2560
#define BN (Bsz*Nn)           // 6624
#define ROWS (BN*Cc)          // 13248 = 414*32
#define XSTRIDE (CONCATk*Cc)  // 5120

typedef unsigned short u16;
typedef __attribute__((ext_vector_type(8))) short bf16x8;
typedef __attribute__((ext_vector_type(4))) float f32x4;

__device__ inline u16 f2b(float f) {
  unsigned u = __builtin_bit_cast(unsigned, f);
  u += 0x7fffu + ((u >> 16) & 1u);          // RNE
  return (u16)(u >> 16);
}
__device__ inline float b2f(u16 b) {
  unsigned u = ((unsigned)b) << 16;
  return __builtin_bit_cast(float, u);
}
__device__ inline void gld16(const void* g, void* l) {
  __builtin_amdgcn_global_load_lds((const __attribute__((address_space(1))) void*)g,
                                   (__attribute__((address_space(3))) void*)l, 16, 0, 0);
}

// ---------------- K1: time gates + h_in + level + zero f_acc ----------------
__global__ __launch_bounds__(128) void k_timegate(
    const float* __restrict__ hist, const float* __restrict__ tod,
    const float* __restrict__ emb,
    const float* __restrict__ w1, const float* __restrict__ b1,
    const float* __restrict__ w2, const float* __restrict__ b2,
    const float* __restrict__ w3, const float* __restrict__ b3,
    float* __restrict__ h_in, float* __restrict__ level,
    float* __restrict__ tgf, float* __restrict__ f_acc)
{
  int bn = blockIdx.x;
  int n = bn % Nn;
  __shared__ float s_in[76];
  __shared__ float s_tg[128];
  __shared__ float s_tgb[12];
  __shared__ float s_h[24];
  int tid = threadIdx.x;
  if (tid < 64) s_in[tid] = emb[n*64 + tid];
  else if (tid < 76) s_in[tid] = tod[bn*12 + (tid - 64)];
  __syncthreads();
  float acc = b1[tid];
#pragma unroll 4
  for (int k = 0; k < 76; ++k) acc = fmaf(s_in[k], w1[k*128 + tid], acc);
  s_tg[tid] = fmaxf(acc, 0.f);
  __syncthreads();
  if (tid < 24) {
    int j = tid % 12;
    const float* w = (tid < 12) ? w2 : w3;
    float a = (tid < 12) ? b2[j] : b3[j];
    for (int k = 0; k < 128; ++k) a = fmaf(s_tg[k], w[k*12 + j], a);
    if (tid < 12) tgf[bn*12 + j] = a;
    else s_tgb[j] = a;
  }
  __syncthreads();
  if (tid < 24) {
    int t = tid >> 1;
    float v = hist[bn*24 + tid] / (1.f + s_tgb[t]);
    h_in[bn*24 + tid] = v;
    s_h[tid] = v;
    f_acc[bn*24 + tid] = 0.f;
  }
  __syncthreads();
  if (tid < 2) {
    float m = s_h[tid];
    for (int t = 1; t < 12; ++t) m = fmaxf(m, s_h[t*2 + tid]);
    level[bn*2 + tid] = m;
  }
}

// ---------------- K2: dp[n,m] = exp(10 * <emb_n, emb_m>) ----------------
__global__ __launch_bounds__(256) void k_dp(const float* __restrict__ emb,
                                            float* __restrict__ dp)
{
  int n = blockIdx.x;
  __shared__ float e[64];
  int tid = threadIdx.x;
  if (tid < 64) e[tid] = emb[n*64 + tid];
  __syncthreads();
  if (tid < Nn) {
    float a = 0.f;
#pragma unroll 8
    for (int k = 0; k < 64; ++k) a = fmaf(e[k], emb[tid*64 + k], a);
    dp[n*Nn + tid] = expf(10.f * a);
  }
}

// ---------------- weight transpose+convert: fp32 [K][N] -> bf16 [N][K] -------
__global__ __launch_bounds__(256) void k_transp(
    const float* __restrict__ src, u16* __restrict__ dst, int K, int N)
{
  int k0 = blockIdx.x*64, n0 = blockIdx.y*64;
  size_t mo = (size_t)blockIdx.z * K * N;
  src += mo; dst += mo;
  __shared__ u16 Ts[64][72];
  int tid = threadIdx.x;
#pragma unroll
  for (int it = 0; it < 4; ++it) {
    int idx = it*256 + tid;
    int r = idx >> 4, q = idx & 15;
    float4 v = *(const float4*)(src + (size_t)(k0 + r)*N + n0 + q*4);
    Ts[r][q*4+0] = f2b(v.x);
    Ts[r][q*4+1] = f2b(v.y);
    Ts[r][q*4+2] = f2b(v.z);
    Ts[r][q*4+3] = f2b(v.w);
  }
  __syncthreads();
#pragma unroll
  for (int it = 0; it < 2; ++it) {
    int idx = it*256 + tid;
    int nl = idx >> 3, kq = idx & 7;
    u16 o[8];
#pragma unroll
    for (int j = 0; j < 8; ++j) o[j] = Ts[kq*8 + j][nl];
    *(bf16x8*)(dst + (size_t)(n0 + nl)*K + k0 + kq*8) = *(bf16x8*)o;
  }
}

// ---------------- build xb bf16, row-major [r=bn*2+c][k] ---------------------
__global__ __launch_bounds__(256) void k_build_b(
    const float* __restrict__ h_in, const float* __restrict__ level,
    const float* __restrict__ dp, const float* __restrict__ emb,
    u16* __restrict__ xb)
{
  int bn = blockIdx.x;
  int b = bn / Nn, n = bn - b*Nn;
  __shared__ float s_dp[Nn];
  int tid = threadIdx.x;
  for (int m = tid; m < Nn; m += 256) s_dp[m] = dp[n*Nn + m];
  __syncthreads();
  float lev[2] = {level[bn*2], level[bn*2+1]};
  float inv[2] = {1.f/(lev[0]+1e-8f), 1.f/(lev[1]+1e-8f)};
  const float* hb = h_in + (size_t)b*Nn*24;
  for (int s = tid; s < 640; s += 256) {
    int c = s / 320, ks = s - c*320;
    u16 o[8];
#pragma unroll
    for (int j = 0; j < 8; ++j) {
      int k = ks*8 + j;
      float v;
      if (k < 12) v = h_in[bn*24 + k*2 + c] * inv[c];
      else if (k < 2496) {
        int q = k - 12; int m = q / 12, t = q - m*12;
        v = fmaxf((hb[m*24 + t*2 + c]*s_dp[m] - lev[c]) * inv[c], 0.f);
      } else v = emb[n*64 + (k - 2496)];
      o[j] = f2b(v);
    }
    *(bf16x8*)(xb + (size_t)(bn*2 + c)*2560 + ks*8) = *(bf16x8*)o;
  }
}

// ---------------- fused N-BEATS block: fc0->h1->h2->h3 + fore + back ---------
// Round-2: counted-vmcnt pipeline (T3+T4). 32-row tiles (grid 414), 4 waves,
// wave tile 16x64 (fc0/h) / 16x32 (back). Both big loops use a 3-buffer
// {A:4KB, B:16KB} LDS pipeline, depth-2 prefetch, raw s_barrier + inline-asm
// s_waitcnt vmcnt(N) (N counts exactly: 5 loads/tile/thread; epilogue stores
// included in the count). All global traffic inside the pipelined loops goes
// through global_load_lds so the compiler emits no vmcnt waits of its own.
// LDS total ~78 KB -> 2 blocks/CU.
template<int FINAL>
__global__ __launch_bounds__(256, 2) void k_mega(
    u16* __restrict__ xb,
    const u16* __restrict__ W0t, const float* __restrict__ b0,
    const u16* __restrict__ W1t, const float* __restrict__ b1,
    const u16* __restrict__ W2t, const float* __restrict__ b2,
    const float* __restrict__ FW, const float* __restrict__ fb,
    const u16* __restrict__ BWt, const float* __restrict__ bbias,
    float* __restrict__ f_acc, float* __restrict__ xf)
{
  __shared__ __attribute__((aligned(16))) u16 Pa[3*2048];   // 12 KB: A / xold slots
  __shared__ __attribute__((aligned(16))) u16 Pb[3*8192];   // 48 KB: B slots (W staging)
  __shared__ __attribute__((aligned(16))) u16 Hs[4096];     //  8 KB: h storage (32x128)
  __shared__ __attribute__((aligned(16))) float Ub[2560];   // 10 KB union: sFw(bf16) / bbias(f32)
  __shared__ float sFb[12];
  u16* sFw = (u16*)Ub;                     // overlaps Ub; used only before bbias staged

  const int tid = threadIdx.x, wv = tid >> 6, lane = tid & 63;
  const int m16 = lane & 15, quad = lane >> 4;
  const int wr = (wv & 1) * 16, wc = (wv >> 1) * 64;   // fc0/h wave tile 16x64
  const int r0 = blockIdx.x * 32;

  // staging geometry (shared by fc0 A and back xold): thread -> (row, 16B chunk)
  const int s_row = tid >> 3, s_ch = tid & 7;
  u16* aw_dst = Pa + wv*512;               // + buf*2048 ; lane scatter adds lane*8 u16
  u16* bw_dst = Pb + wv*512;               // + buf*8192 + it*2048

  // ---- fc0 sources: A = xb rows (pre-swizzled col chunk), B = W0t panel ----
  const u16* a_src = xb + (size_t)(r0 + s_row)*2560 + ((s_ch ^ (s_row & 7))*8);
  const u16* b0_src[4];
#pragma unroll
  for (int it = 0; it < 4; ++it) {
    int slot = it*256 + tid, nl = slot >> 3, g = (slot & 7) ^ (nl & 7);
    b0_src[it] = W0t + (size_t)nl*2560 + g*8;
  }
  auto issueF = [&](int t, int buf) {
    gld16(a_src + t*64, aw_dst + buf*2048);
#pragma unroll
    for (int it = 0; it < 4; ++it)
      gld16(b0_src[it] + t*64, bw_dst + buf*8192 + it*2048);
  };

  issueF(0, 0); issueF(1, 1);              // 10 vmem/thread outstanding

  f32x4 acc[4] = {};
  for (int j = 0; j < 40; ++j) {
    const int buf = j % 3;
    if (j < 39) asm volatile("s_waitcnt vmcnt(5)" ::: "memory");  // tile j landed
    else        asm volatile("s_waitcnt vmcnt(0)" ::: "memory");
    __builtin_amdgcn_sched_barrier(0);
    __builtin_amdgcn_s_barrier();
    __builtin_amdgcn_sched_barrier(0);
    if (j < 38) issueF(j + 2, (j + 2) % 3);   // into buffer freed last iter
    const u16* Ab = Pa + buf*2048;
    const u16* Bb = Pb + buf*8192;
#pragma unroll
    for (int ks = 0; ks < 2; ++ks) {
      int cb = ks*4 + quad;
      int ar = wr + m16;
      bf16x8 a = *(const bf16x8*)&Ab[(ar*8 + (cb ^ (ar & 7)))*8];
#pragma unroll
      for (int jj = 0; jj < 4; ++jj) {
        int nl = wc + jj*16 + m16;
        bf16x8 b = *(const bf16x8*)&Bb[(nl*8 + (cb ^ (nl & 7)))*8];
        acc[jj] = __builtin_amdgcn_mfma_f32_16x16x32_bf16(a, b, acc[jj], 0, 0, 0);
      }
    }
  }

  // ---- h-phase helpers (K=128, 16 chunks, XOR-16 swizzle; W = 32KB in Pb) ----
  auto stageW = [&](const u16* W) {
#pragma unroll
    for (int it = 0; it < 8; ++it) {
      int slot = it*256 + tid, nl = slot >> 4, g = (slot & 15) ^ (nl & 15);
      gld16(W + (size_t)nl*128 + g*8, Pb + it*2048 + wv*512);
    }
  };
  auto writeH = [&](const f32x4* ac, const float* bias) {
#pragma unroll
    for (int jj = 0; jj < 4; ++jj) {
      int col = wc + jj*16 + m16;
      float bv = bias[col];
#pragma unroll
      for (int reg = 0; reg < 4; ++reg) {
        int row = wr + quad*4 + reg;
        int chunk = col >> 3;
        Hs[(row*16 + (chunk ^ (row & 15)))*8 + (col & 7)] =
            f2b(fmaxf(ac[jj][reg] + bv, 0.f));
      }
    }
  };
  auto mm128 = [&](f32x4* ac) {
#pragma unroll
    for (int ks = 0; ks < 4; ++ks) {
      int cb = ks*4 + quad;
      int ar = wr + m16;
      bf16x8 a = *(const bf16x8*)&Hs[(ar*16 + (cb ^ (ar & 15)))*8];
#pragma unroll
      for (int jj = 0; jj < 4; ++jj) {
        int nl = wc + jj*16 + m16;
        bf16x8 b = *(const bf16x8*)&Pb[(nl*16 + (cb ^ (nl & 15)))*8];
        ac[jj] = __builtin_amdgcn_mfma_f32_16x16x32_bf16(a, b, ac[jj], 0, 0, 0);
      }
    }
  };

  __syncthreads();                 // fc0 LDS reads done; drains all vmem
  stageW(W1t);
  for (int s = tid; s < 1536; s += 256) sFw[s] = f2b(FW[s]);
  if (tid < 12) sFb[tid] = fb[tid];
  writeH(acc, b0);                 // h1 -> Hs
  __syncthreads();

  f32x4 acc2[4] = {};
  mm128(acc2);
  __syncthreads();
  stageW(W2t);
  writeH(acc2, b1);                // h2 -> Hs
  __syncthreads();

  f32x4 acc3[4] = {};
  mm128(acc3);
  __syncthreads();
  writeH(acc3, b2);                // h3 -> Hs (stays for back phase)
  __syncthreads();

  // ---- forecast accumulation (before back pipeline; keeps vmcnt clean) ----
  for (int o = tid; o < 384; o += 256) {
    int row = o / 12, t = o - (o/12)*12;
    float a = sFb[t];
#pragma unroll
    for (int chunk = 0; chunk < 16; ++chunk) {
      const u16* hp = &Hs[(row*16 + (chunk ^ (row & 15)))*8];
#pragma unroll
      for (int jq = 0; jq < 8; ++jq)
        a = fmaf(b2f(hp[jq]), b2f(sFw[(chunk*8 + jq)*12 + t]), a);
    }
    f_acc[(size_t)(r0 + row)*12 + t] += a;
  }
  __syncthreads();                 // fore done; U free; vmem drained

  // ---- back pipeline prologue: bbias (3/thread) then tiles 0,1 (5 each) ----
#pragma unroll
  for (int it = 0; it < 3; ++it) {
    int slot = it*256 + tid;
    if (slot < 640)                // it=2: tid<128 -> wave-uniform predicate
      gld16(bbias + slot*4, Ub + (it*256 + wv*64)*4);
  }
  const u16* xo_src = xb + (size_t)(r0 + s_row)*2560 + ((s_ch ^ (s_row & 7))*8);
  const u16* bw_src[4];
#pragma unroll
  for (int it = 0; it < 4; ++it) {
    int slot = it*256 + tid, nl = slot >> 4, g = (slot & 15) ^ (nl & 15);
    bw_src[it] = BWt + (size_t)nl*128 + g*8;
  }
  auto issueB = [&](int t, int buf) {
    gld16(xo_src + t*64, aw_dst + buf*2048);
#pragma unroll
    for (int it = 0; it < 4; ++it)
      gld16(bw_src[it] + (size_t)t*8192, bw_dst + buf*8192 + it*2048);
  };
  issueB(0, 0); issueB(1, 1);

  // ---- back loop: 40 tiles of 64 cols; wave tile 16 rows x 32 cols ----
  const int wrB = (wv & 1) * 16, wcB = (wv >> 1) * 32;
  for (int j = 0; j < 40; ++j) {
    const int buf = j % 3;
    if (j == 0)       asm volatile("s_waitcnt vmcnt(5)" ::: "memory");
    else if (j < 39) {
      if constexpr (FINAL) asm volatile("s_waitcnt vmcnt(9)" ::: "memory");
      else                 asm volatile("s_waitcnt vmcnt(6)" ::: "memory");
    } else            asm volatile("s_waitcnt vmcnt(0)" ::: "memory");
    __builtin_amdgcn_sched_barrier(0);
    __builtin_amdgcn_s_barrier();
    __builtin_amdgcn_sched_barrier(0);
    if (j < 38) issueB(j + 2, (j + 2) % 3);

    f32x4 bacc[2] = {};
#pragma unroll
    for (int ks = 0; ks < 4; ++ks) {
      int cb = ks*4 + quad;
      int ar = wrB + m16;
      bf16x8 a = *(const bf16x8*)&Hs[(ar*16 + (cb ^ (ar & 15)))*8];
#pragma unroll
      for (int jj = 0; jj < 2; ++jj) {
        int nl = wcB + jj*16 + m16;
        bf16x8 b = *(const bf16x8*)&Pb[buf*8192 + (nl*16 + (cb ^ (nl & 15)))*8];
        bacc[jj] = __builtin_amdgcn_mfma_f32_16x16x32_bf16(a, b, bacc[jj], 0, 0, 0);
      }
    }
    const int n0 = j*64;
    if constexpr (FINAL) {
#pragma unroll
      for (int jj = 0; jj < 2; ++jj) {
        int col = wcB + jj*16 + m16, gcol = n0 + col;
        float bb = Ub[gcol];
#pragma unroll
        for (int pr = 0; pr < 2; ++pr) {
          int row0 = wrB + quad*4 + pr*2;   // even row; (row0,row0+1) = same bn, c=0/1
          float o0 = b2f(Pa[buf*2048 + (row0*8 + ((col>>3) ^ (row0 & 7)))*8 + (col & 7)]);
          float o1 = b2f(Pa[buf*2048 + ((row0+1)*8 + ((col>>3) ^ ((row0+1) & 7)))*8 + (col & 7)]);
          float2 ov;
          ov.x = fmaxf(o0 - (bacc[jj][pr*2+0] + bb), 0.f);
          ov.y = fmaxf(o1 - (bacc[jj][pr*2+1] + bb), 0.f);
          int bn = (r0 + row0) >> 1;
          *(float2*)(xf + (size_t)bn*XSTRIDE + (size_t)gcol*2) = ov;
        }
      }
    } else {
      // RMW through the xold slot: scalar update in LDS, then coalesced 16B store
#pragma unroll
      for (int jj = 0; jj < 2; ++jj) {
        int col = wcB + jj*16 + m16, gcol = n0 + col;
        float bb = Ub[gcol];
#pragma unroll
        for (int reg = 0; reg < 4; ++reg) {
          int row = wrB + quad*4 + reg;
          int off = buf*2048 + (row*8 + ((col>>3) ^ (row & 7)))*8 + (col & 7);
          float nv = fmaxf(b2f(Pa[off]) - (bacc[jj][reg] + bb), 0.f);
          Pa[off] = f2b(nv);
        }
      }
      asm volatile("s_waitcnt lgkmcnt(0)" ::: "memory");
      __builtin_amdgcn_s_barrier();
      __builtin_amdgcn_sched_barrier(0);
      bf16x8 v = *(const bf16x8*)&Pa[buf*2048 + (s_row*8 + (s_ch ^ (s_row & 7)))*8];
      *(bf16x8*)(xb + (size_t)(r0 + s_row)*2560 + n0 + s_ch*8) = v;
    }
  }
}

// ---------------- finalize forecast ----------------
__global__ __launch_bounds__(256) void k_forecast(
    const float* __restrict__ f_acc, const float* __restrict__ level,
    const float* __restrict__ tgf, float* __restrict__ outf)
{
  int idx = blockIdx.x*256 + threadIdx.x;
  if (idx >= BN*24) return;
  int bn = idx / 24;
  int rem = idx - bn*24;
  int t = rem >> 1, c = rem & 1;
  float v = f_acc[bn*24 + c*12 + t];
  outf[idx] = v * level[bn*2 + c] * (1.f + tgf[bn*12 + t]);
}

extern "C" void kernel_launch(void* const* d_in, const int* in_sizes, int n_in,
                              void* d_out, int out_size, void* d_ws, size_t ws_size,
                              hipStream_t stream)
{
  const float* hist = (const float*)d_in[0];
  const float* tod  = (const float*)d_in[1];
  const float* emb  = (const float*)d_in[2];
  const float* tg1w = (const float*)d_in[3];
  const float* tg1b = (const float*)d_in[4];
  const float* tg2w = (const float*)d_in[5];
  const float* tg2b = (const float*)d_in[6];
  const float* tg3w = (const float*)d_in[7];
  const float* tg3b = (const float*)d_in[8];
  const float* fc0w = (const float*)d_in[9];
  const float* fc0b = (const float*)d_in[10];
  const float* fcw  = (const float*)d_in[11];
  const float* fcb  = (const float*)d_in[12];
  const float* forew= (const float*)d_in[13];
  const float* foreb= (const float*)d_in[14];
  const float* backw= (const float*)d_in[15];
  const float* backb= (const float*)d_in[16];

  char* w = (char*)d_ws;
  float* h_in  = (float*)w; w += 635904;     // 158976 f32
  float* level = (float*)w; w += 52992;      // 13248 f32
  float* tgf   = (float*)w; w += 317952;     // 79488 f32
  float* dp    = (float*)w; w += 171408;     // 42852 f32
  float* f_acc = (float*)w; w += 635904;     // 158976 f32
  u16* fc0wt   = (u16*)w;   w += 1966080;    // 3 x [128][2560]
  u16* fcwt    = (u16*)w;   w += 196608;     // 6 x [128][128]
  u16* backwt  = (u16*)w;   w += 1966080;    // 3 x [2560][128]
  u16* xb      = (u16*)w;   w += 67829760;   // 13248*2560 bf16

  float* x    = (float*)d_out;                               // [bn][k][c] fp32
  float* outf = (float*)d_out + (size_t)BN*CONCATk*Cc;

  k_transp<<<dim3(40, 2, 3), 256, 0, stream>>>(fc0w, fc0wt, 2560, 128);
  k_transp<<<dim3(2, 2, 6), 256, 0, stream>>>(fcw, fcwt, 128, 128);
  k_transp<<<dim3(2, 40, 3), 256, 0, stream>>>(backw, backwt, 128, 2560);
  k_timegate<<<BN, 128, 0, stream>>>(hist, tod, emb, tg1w, tg1b, tg2w, tg2b,
                                     tg3w, tg3b, h_in, level, tgf, f_acc);
  k_dp<<<Nn, 256, 0, stream>>>(emb, dp);
  k_build_b<<<BN, 256, 0, stream>>>(h_in, level, dp, emb, xb);

  for (int i = 0; i < NBb; ++i) {
    const u16* W0t = fc0wt + (size_t)i*327680;
    const u16* W1t = fcwt + (size_t)(i*2+0)*16384;
    const u16* W2t = fcwt + (size_t)(i*2+1)*16384;
    const u16* BWt = backwt + (size_t)i*327680;
    if (i < NBb-1)
      k_mega<0><<<414, 256, 0, stream>>>(
          xb, W0t, fc0b + i*128, W1t, fcb + (i*2+0)*128, W2t, fcb + (i*2+1)*128,
          forew + (size_t)i*1536, foreb + i*12, BWt, backb + (size_t)i*2560,
          f_acc, nullptr);
    else
      k_mega<1><<<414, 256, 0, stream>>>(
          xb, W0t, fc0b + i*128, W1t, fcb + (i*2+0)*128, W2t, fcb + (i*2+1)*128,
          forew + (size_t)i*1536, foreb + i*12, BWt, backb + (size_t)i*2560,
          f_acc, x);
  }
  k_forecast<<<(BN*24 + 255)/256, 256, 0, stream>>>(f_acc, level, tgf, outf);
}